// Round 12
// baseline (311.955 us; speedup 1.0000x reference)
//
#include <hip/hip_runtime.h>
#include <hip/hip_bf16.h>
#include <stdint.h>

typedef __bf16 bf16x8 __attribute__((ext_vector_type(8)));
typedef float f32x4 __attribute__((ext_vector_type(4)));

#define T_SEQ 4096
#define C_DIM 1024
#define H_NUM 16
#define HD 64
#define C3 3072
#define QKS 2048                 // qk buffer row stride (q | k)
#define NEG_BIG (-30000.0f)

__device__ __forceinline__ unsigned short f2bf(float f) {
    uint32_t u = __builtin_bit_cast(uint32_t, f);
    u += 0x7fffu + ((u >> 16) & 1u);
    return (unsigned short)(u >> 16);
}

__device__ __forceinline__ uint32_t pk_bf16(float a, float b) {
    __hip_bfloat162 h = __float22bfloat162_rn(float2{a, b});
    uint32_t u;
    __builtin_memcpy(&u, &h, sizeof(u));
    return u;
}

__device__ __forceinline__ bf16x8 ld_bf8(const unsigned short* p) {
    return *reinterpret_cast<const bf16x8*>(p);
}

__device__ __forceinline__ void async_g2l16(const unsigned short* g, unsigned short* l) {
    __builtin_amdgcn_global_load_lds(
        (const __attribute__((address_space(1))) void*)g,
        (__attribute__((address_space(3))) void*)l, 16, 0, 0);
}

__device__ __forceinline__ void store_c(unsigned short* C, size_t idx, float v) { C[idx] = f2bf(v); }
__device__ __forceinline__ void store_c(float* C, size_t idx, float v)          { C[idx] = v; }

__device__ __forceinline__ void cvt8(const float* src, unsigned short* dst) {
    float4 f0 = *(const float4*)src;
    float4 f1 = *(const float4*)(src + 4);
    union { uint32_t w[4]; uint4 q; } t;
    t.w[0] = pk_bf16(f0.x, f0.y);
    t.w[1] = pk_bf16(f0.z, f0.w);
    t.w[2] = pk_bf16(f1.x, f1.y);
    t.w[3] = pk_bf16(f1.z, f1.w);
    *(uint4*)dst = t.q;
}

#define XN (T_SEQ * C_DIM)
#define WAN (C3 * C_DIM)
#define WPN (C_DIM * C_DIM)

// all three fp32 weights/inputs -> bf16 in one launch
__global__ void cvt_all(const float* __restrict__ x, const float* __restrict__ wa,
                        const float* __restrict__ wp,
                        unsigned short* __restrict__ xb, unsigned short* __restrict__ wab,
                        unsigned short* __restrict__ wpb) {
    int i = (blockIdx.x * blockDim.x + threadIdx.x) * 8;
    if (i < XN) cvt8(x + i, xb + i);
    else if (i < XN + WAN) { int k = i - XN; cvt8(wa + k, wab + k); }
    else { int k = i - XN - WAN; if (k < WPN) cvt8(wp + k, wpb + k); }
}

// C = A @ B^T, bf16, m97 async staging. 128x128 tile, BK=32.
template <typename TC>
__global__ __launch_bounds__(256, 2) void gemm_bt(
    const unsigned short* __restrict__ A, const unsigned short* __restrict__ B,
    TC* __restrict__ C, int M, int N, int K)
{
    __shared__ __attribute__((aligned(16))) unsigned short As[128 * 32];
    __shared__ __attribute__((aligned(16))) unsigned short Bs[128 * 32];

    const int tid  = threadIdx.x;
    const int wave = tid >> 6, lane = tid & 63;
    const int quad = lane >> 4, l16 = lane & 15;
    const int wm = wave >> 1, wn = wave & 1;
    const int m0 = blockIdx.y * 128, n0 = blockIdx.x * 128;

    const int srow = wave * 32 + (lane >> 2);
    const int scol = (lane & 3) * 8;

    f32x4 acc[4][4] = {};

    for (int k0 = 0; k0 < K; k0 += 32) {
        {
            const unsigned short* ga = A + (size_t)(m0 + srow) * K + k0 + scol;
            const unsigned short* gb = B + (size_t)(n0 + srow) * K + k0 + scol;
            unsigned short* la = As + (wave * 32) * 32;
            unsigned short* lb = Bs + (wave * 32) * 32;
            async_g2l16(ga, la);
            async_g2l16(ga + (size_t)16 * K, la + 16 * 32);
            async_g2l16(gb, lb);
            async_g2l16(gb + (size_t)16 * K, lb + 16 * 32);
        }
        __syncthreads();

        bf16x8 af[4], bf[4];
        #pragma unroll
        for (int i = 0; i < 4; ++i) {
            af[i] = ld_bf8(As + (wm * 64 + i * 16 + l16) * 32 + quad * 8);
            bf[i] = ld_bf8(Bs + (wn * 64 + i * 16 + l16) * 32 + quad * 8);
        }
        #pragma unroll
        for (int mt = 0; mt < 4; ++mt)
            #pragma unroll
            for (int nt = 0; nt < 4; ++nt)
                acc[mt][nt] = __builtin_amdgcn_mfma_f32_16x16x32_bf16(
                    af[mt], bf[nt], acc[mt][nt], 0, 0, 0);
        __syncthreads();
    }

    #pragma unroll
    for (int mt = 0; mt < 4; ++mt)
        #pragma unroll
        for (int nt = 0; nt < 4; ++nt)
            #pragma unroll
            for (int r = 0; r < 4; ++r) {
                int row = m0 + wm * 64 + mt * 16 + quad * 4 + r;
                int col = n0 + wn * 64 + nt * 16 + l16;
                store_c(C, (size_t)row * N + col, acc[mt][nt][r]);
            }
}

// One flash tile, 32 q-rows/wave, max-free softmax, V fragments from global.
template <bool MASK>
__device__ __forceinline__ void fa9_tile(
    const unsigned short* Ksb, const bf16x8 vf[4][2], unsigned short* pbuf,
    const bf16x8 qf[2][2], f32x4 o[2][4], float* l_part,
    int k0, int q_abs0, int quad, int l16, int sw, int fo0, int fo1)
{
    const unsigned short* krow = Ksb + l16 * 64;
    bf16x8 kf[4][2];
    #pragma unroll
    for (int s = 0; s < 4; ++s) {
        kf[s][0] = ld_bf8(krow + s * 1024 + fo0);
        kf[s][1] = ld_bf8(krow + s * 1024 + fo1);
    }

    #pragma unroll
    for (int qs = 0; qs < 2; ++qs) {
        f32x4 st[4];
        #pragma unroll
        for (int s = 0; s < 4; ++s) {
            f32x4 z = {};
            z = __builtin_amdgcn_mfma_f32_16x16x32_bf16(kf[s][0], qf[qs][0], z, 0, 0, 0);
            st[s] = __builtin_amdgcn_mfma_f32_16x16x32_bf16(kf[s][1], qf[qs][1], z, 0, 0, 0);
        }
        float ts = 0.f;
        #pragma unroll
        for (int s = 0; s < 4; ++s)
            #pragma unroll
            for (int r = 0; r < 4; ++r) {
                float v = st[s][r];
                if (MASK) {
                    int key = k0 + s * 16 + quad * 4 + r;
                    v = (key <= q_abs0 + qs * 16) ? v : NEG_BIG;
                }
                float e = __builtin_amdgcn_exp2f(v);   // exp2(-30000) = 0
                st[s][r] = e;
                ts += e;
            }
        l_part[qs] += ts;

        unsigned short* prow = pbuf + (qs * 16 + l16) * 64;
        #pragma unroll
        for (int s = 0; s < 4; ++s) {
            int g = 2 * s + (quad >> 1);
            uint2 pk;
            pk.x = pk_bf16(st[s][0], st[s][1]);
            pk.y = pk_bf16(st[s][2], st[s][3]);
            *(uint2*)((char*)prow + (g ^ sw) * 16 + 8 * (quad & 1)) = pk;
        }
    }

    #pragma unroll
    for (int qs = 0; qs < 2; ++qs) {
        const unsigned short* prow = pbuf + (qs * 16 + l16) * 64;
        bf16x8 pf0 = ld_bf8(prow + fo0);
        bf16x8 pf1 = ld_bf8(prow + fo1);
        #pragma unroll
        for (int c = 0; c < 4; ++c) {
            o[qs][c] = __builtin_amdgcn_mfma_f32_16x16x32_bf16(vf[c][0], pf0, o[qs][c], 0, 0, 0);
            o[qs][c] = __builtin_amdgcn_mfma_f32_16x16x32_bf16(vf[c][1], pf1, o[qs][c], 0, 0, 0);
        }
    }
}

// Flash v9: 4-wave blocks, 128 q-rows, 512 equal-work blocks, dbuf K staging
// (LDS), V fragments DIRECT from global (line-coalesced Vt rows), max-free
// softmax. LDS 32KB.
__global__ __launch_bounds__(256, 3) void flash_attn9(
    const unsigned short* __restrict__ qk,
    const unsigned short* __restrict__ Vt,
    unsigned short* __restrict__ Y)
{
    __shared__ __attribute__((aligned(16))) unsigned short Ks[2][64 * 64];
    __shared__ __attribute__((aligned(16))) unsigned short Pl[4][32 * 64];

    const int tid  = threadIdx.x;
    const int wave = tid >> 6, lane = tid & 63;
    const int quad = lane >> 4, l16 = lane & 15;

    // 512 blocks: slot (h, j) x 2 rounds; qb = {j, 31-j} -> equal work.
    const int bi = blockIdx.x;
    const int rr = bi >> 8, ss = bi & 255;
    const int h  = ss & 15;
    const int j  = ss >> 4;
    const int qb = rr ? (31 - j) : j;

    const int q0w    = qb * 128 + wave * 32;
    const int q_abs0 = q0w + l16;
    const int sw  = l16 & 7;
    const int fo0 = (quad ^ sw) * 8;
    const int fo1 = ((quad + 4) ^ sw) * 8;

    // Q fragments (B-operand), prescaled by 0.125*log2(e)
    bf16x8 qf[2][2];
    {
        const float QS = 0.125f * 1.44269504f;
        #pragma unroll
        for (int qs = 0; qs < 2; ++qs) {
            const unsigned short* qp =
                qk + (size_t)(q0w + qs * 16 + l16) * QKS + h * HD + quad * 8;
            bf16x8 a = ld_bf8(qp), b = ld_bf8(qp + 32);
            #pragma unroll
            for (int i = 0; i < 8; ++i) {
                qf[qs][0][i] = (__bf16)((float)a[i] * QS);
                qf[qs][1][i] = (__bf16)((float)b[i] * QS);
            }
        }
    }

    // K staging: wave stages 16 rows/tile (2 calls), XOR chunk swizzle
    const int srow = lane >> 3;
    const int schunk = (lane & 7) ^ srow;
    const unsigned short* kp0 =
        qk + (size_t)(wave * 16 + srow) * QKS + C_DIM + h * HD + schunk * 8;
    const unsigned short* kp1 = kp0 + (size_t)8 * QKS;
    unsigned short* lk0  = Ks[0] + (wave * 16) * 64;
    unsigned short* lk0b = lk0 + 8 * 64;
    const int lds_db = 64 * 64;

    // V direct-load base: lane reads Vt rows (h*64 + c*16 + l16), 16B chunks
    const unsigned short* vb = Vt + (size_t)(h * HD + l16) * T_SEQ + quad * 8;

    f32x4 o[2][4] = {};
    float l_part[2] = {0.f, 0.f};
    unsigned short* pbuf = Pl[wave];

    const int ntiles = 2 * qb + 2;
    const int mask_t = 2 * qb + (wave >> 1);   // waves 0,1 end at 2qb; 2,3 at 2qb+1

    async_g2l16(kp0, lk0);  async_g2l16(kp1, lk0b);
    kp0 += (size_t)64 * QKS; kp1 += (size_t)64 * QKS;

    for (int t = 0; t < ntiles; ++t) {
        __syncthreads();
        const int b = t & 1;
        const bool active = (t <= mask_t);     // wave-uniform

        // V prefetch for tile t (global, full-line-coalesced), issued first
        bf16x8 vf[4][2];
        if (active) {
            const unsigned short* v0 = vb + t * 64;
            #pragma unroll
            for (int c = 0; c < 4; ++c) {
                vf[c][0] = ld_bf8(v0 + (size_t)(c * 16) * T_SEQ);
                vf[c][1] = ld_bf8(v0 + (size_t)(c * 16) * T_SEQ + 32);
            }
        }

        if (t + 1 < ntiles) {
            const int nb = 1 - b;
            async_g2l16(kp0, lk0 + nb * lds_db);
            async_g2l16(kp1, lk0b + nb * lds_db);
            kp0 += (size_t)64 * QKS; kp1 += (size_t)64 * QKS;
        }

        if (active) {
            if (t < mask_t)
                fa9_tile<false>(Ks[b], vf, pbuf, qf, o, l_part,
                                t * 64, q_abs0, quad, l16, sw, fo0, fo1);
            else
                fa9_tile<true>(Ks[b], vf, pbuf, qf, o, l_part,
                               t * 64, q_abs0, quad, l16, sw, fo0, fo1);
        }
    }

    #pragma unroll
    for (int qs = 0; qs < 2; ++qs) {
        float l = l_part[qs];
        l += __shfl_xor(l, 16, 64);
        l += __shfl_xor(l, 32, 64);
        float inv_l = 1.f / l;
        #pragma unroll
        for (int c = 0; c < 4; ++c) {
            union { uint32_t w[2]; uint2 q; } t;
            t.w[0] = pk_bf16(o[qs][c][0] * inv_l, o[qs][c][1] * inv_l);
            t.w[1] = pk_bf16(o[qs][c][2] * inv_l, o[qs][c][3] * inv_l);
            *(uint2*)(Y + (size_t)(q_abs0 + qs * 16) * C_DIM + h * HD + c * 16 + quad * 4) = t.q;
        }
    }
}

extern "C" void kernel_launch(void* const* d_in, const int* in_sizes, int n_in,
                              void* d_out, int out_size, void* d_ws, size_t ws_size,
                              hipStream_t stream) {
    const float* x      = (const float*)d_in[0];   // [4096,1024] fp32
    const float* w_attn = (const float*)d_in[1];   // [3072,1024] fp32
    const float* w_proj = (const float*)d_in[2];   // [1024,1024] fp32
    float* out = (float*)d_out;                    // [4096,1024] fp32 (16MB)

    // ws (>=32MB): qk bf16 [4096,2048] 16MB | xb bf16 8MB (y aliases after
    // gemm_vt) | wpb bf16 2MB
    unsigned short* qk  = (unsigned short*)d_ws;
    unsigned short* xb  = qk + (size_t)T_SEQ * QKS;
    unsigned short* y   = xb;                           // xb dead after gemm_vt
    unsigned short* wpb = xb + (size_t)T_SEQ * C_DIM;
    // d_out scratch (dead until gemm2): Vt bf16 [1024][4096] 8MB | wab 6MB
    unsigned short* Vt  = (unsigned short*)d_out;
    unsigned short* wab = Vt + (size_t)C_DIM * T_SEQ;
    unsigned short* wvb = wab + (size_t)2048 * C_DIM;   // v-weight rows of w_attn

    // all converts in one launch
    cvt_all<<<(XN + WAN + WPN) / 8 / 256, 256, 0, stream>>>(x, w_attn, w_proj, xb, wab, wpb);

    // qk = xb @ [wq;wk]^T   [4096, 2048]
    gemm_bt<unsigned short>
        <<<dim3(QKS / 128, T_SEQ / 128), 256, 0, stream>>>(xb, wab, qk, T_SEQ, QKS, C_DIM);

    // Vt = wv @ xb^T        [1024, 4096]  (transposed V, coalesced writes)
    gemm_bt<unsigned short>
        <<<dim3(T_SEQ / 128, C_DIM / 128), 256, 0, stream>>>(wvb, xb, Vt, C_DIM, T_SEQ, C_DIM);

    // y = attention(qk, Vt)
    flash_attn9<<<dim3(512), 256, 0, stream>>>(qk, Vt, y);

    // out = y @ wpb^T (fp32)
    gemm_bt<float>
        <<<dim3(C_DIM / 128, T_SEQ / 128), 256, 0, stream>>>(y, wpb, out, T_SEQ, C_DIM, C_DIM);
}